// Round 2
// baseline (62.514 us; speedup 1.0000x reference)
//
#include <hip/hip_runtime.h>
#include <math.h>

#define N_PTS 65536
#define N_CTR 1024
#define CHUNK 256        // centers per block (4 chunks)
#define PPB   512        // points per block (256 threads x 2 points)

#if __has_builtin(__builtin_amdgcn_exp2f)
#define EXP2(x) __builtin_amdgcn_exp2f(x)
#else
#define EXP2(x) exp2f(x)
#endif

// Exponent as polynomial in (x, x^2, y, y^2):
//   s = za + zb*x + zc*x^2 + zd*y + ze*y^2   (log2e folded in)
// Derivative sums split so accumulation is pure FMA:
//   sum p*(x-cx)*e = x * sum(p*e) + sum((-p*cx)*e)
__global__ __launch_bounds__(256) void srbf_kernel(
    const float* __restrict__ x,
    const float* __restrict__ h0, const float* __restrict__ c0, const float* __restrict__ w0,
    const float* __restrict__ h1, const float* __restrict__ c1, const float* __restrict__ w1,
    const float* __restrict__ h2, const float* __restrict__ c2, const float* __restrict__ w2,
    float* __restrict__ out)
{
    __shared__ float4 sA[CHUNK];   // (zb, zc, zd, ze)
    __shared__ float4 sB[CHUNK];   // (za, k0, k1, k2)
    __shared__ float  sC[CHUNK];   // k3 (set 0 only)

    const int bid   = blockIdx.x;
    const int set   = bid >> 9;          // 512 blocks per set
    const int r     = bid & 511;
    const int chunk = r >> 7;            // 4 center-chunks
    const int pblk  = r & 127;           // 128 point-blocks
    const int tid   = threadIdx.x;

    const float*  __restrict__ h = (set == 0) ? h0 : ((set == 1) ? h1 : h2);
    const float2* __restrict__ c = (const float2*)((set == 0) ? c0 : ((set == 1) ? c1 : c2));
    const float2* __restrict__ w = (const float2*)((set == 0) ? w0 : ((set == 1) ? w1 : w2));

    const float LOG2E = 1.4426950408889634f;

    // Stage folded constants: one center per thread.
    {
        const int j = chunk * CHUNK + tid;
        float2 cj = c[j];
        float2 wj = w[j];
        float  hh = h[j];
        float d1 = wj.x * wj.x;
        float d2 = wj.y * wj.y;
        float zb =  2.f * cj.x * d1 * LOG2E;
        float zc = -d1 * LOG2E;
        float zd =  2.f * cj.y * d2 * LOG2E;
        float ze = -d2 * LOG2E;
        float za = -(cj.x * cj.x * d1 + cj.y * cj.y * d2) * LOG2E;
        float k0, k1, k2, k3;
        if (set == 0) {
            k0 = -2.f * hh * d1;          // p0  (ux slope)
            k1 =  2.f * hh * d1 * cj.x;   // q0
            k2 = -2.f * hh * d2;          // p1  (uy slope)
            k3 =  2.f * hh * d2 * cj.y;   // q1
        } else if (set == 1) {
            k0 = hh;                       // P
            k1 = -2.f * hh * d1;          // Px slope
            k2 =  2.f * hh * d1 * cj.x;   // Px offset
            k3 = 0.f;
        } else {
            k0 = hh;                       // Q
            k1 = -2.f * hh * d2;          // Qy slope
            k2 =  2.f * hh * d2 * cj.y;   // Qy offset
            k3 = 0.f;
        }
        sA[tid] = make_float4(zb, zc, zd, ze);
        sB[tid] = make_float4(za, k0, k1, k2);
        sC[tid] = k3;
    }
    __syncthreads();

    const int i0 = pblk * PPB + tid;
    const int i1 = i0 + 256;
    const float2 Pa = ((const float2*)x)[i0];
    const float2 Pb = ((const float2*)x)[i1];
    const float xa = Pa.x, ya = Pa.y, xb = Pb.x, yb = Pb.y;
    const float xa2 = xa * xa, ya2 = ya * ya, xb2 = xb * xb, yb2 = yb * yb;

    if (set == 0) {
        float aP0 = 0.f, aQ0 = 0.f, aP1 = 0.f, aQ1 = 0.f;
        float bP0 = 0.f, bQ0 = 0.f, bP1 = 0.f, bQ1 = 0.f;
        #pragma unroll 4
        for (int jj = 0; jj < CHUNK; ++jj) {
            float4 A = sA[jj];
            float4 B = sB[jj];
            float  k3 = sC[jj];
            float sa = fmaf(xa, A.x, B.x);
            sa = fmaf(xa2, A.y, sa);
            sa = fmaf(ya,  A.z, sa);
            sa = fmaf(ya2, A.w, sa);
            float sb = fmaf(xb, A.x, B.x);
            sb = fmaf(xb2, A.y, sb);
            sb = fmaf(yb,  A.z, sb);
            sb = fmaf(yb2, A.w, sb);
            float ea = EXP2(sa);
            float eb = EXP2(sb);
            aP0 = fmaf(B.y, ea, aP0);  aQ0 = fmaf(B.z, ea, aQ0);
            aP1 = fmaf(B.w, ea, aP1);  aQ1 = fmaf(k3,  ea, aQ1);
            bP0 = fmaf(B.y, eb, bP0);  bQ0 = fmaf(B.z, eb, bQ0);
            bP1 = fmaf(B.w, eb, bP1);  bQ1 = fmaf(k3,  eb, bQ1);
        }
        atomicAdd(&out[i0],          fmaf(xa, aP0, aQ0));   // ux(a)
        atomicAdd(&out[N_PTS + i0],  fmaf(ya, aP1, aQ1));   // uy(a)
        atomicAdd(&out[i1],          fmaf(xb, bP0, bQ0));   // ux(b)
        atomicAdd(&out[N_PTS + i1],  fmaf(yb, bP1, bQ1));   // uy(b)
    } else {
        // set 1: P = sum(k0*e), Px = x*sum(k1*e)+sum(k2*e)
        // set 2: Q = sum(k0*e), Qy = y*sum(k1*e)+sum(k2*e)
        float aU = 0.f, aP = 0.f, aQ = 0.f;
        float bU = 0.f, bP = 0.f, bQ = 0.f;
        #pragma unroll 4
        for (int jj = 0; jj < CHUNK; ++jj) {
            float4 A = sA[jj];
            float4 B = sB[jj];
            float sa = fmaf(xa, A.x, B.x);
            sa = fmaf(xa2, A.y, sa);
            sa = fmaf(ya,  A.z, sa);
            sa = fmaf(ya2, A.w, sa);
            float sb = fmaf(xb, A.x, B.x);
            sb = fmaf(xb2, A.y, sb);
            sb = fmaf(yb,  A.z, sb);
            sb = fmaf(yb2, A.w, sb);
            float ea = EXP2(sa);
            float eb = EXP2(sb);
            aU = fmaf(B.y, ea, aU);
            aP = fmaf(B.z, ea, aP);
            aQ = fmaf(B.w, ea, aQ);
            bU = fmaf(B.y, eb, bU);
            bP = fmaf(B.z, eb, bP);
            bQ = fmaf(B.w, eb, bQ);
        }
        float* o = out + (size_t)set * 2 * N_PTS;
        const float ga = (set == 1) ? xa : ya;
        const float gb = (set == 1) ? xb : yb;
        atomicAdd(&o[i0],         aU);
        atomicAdd(&o[N_PTS + i0], fmaf(ga, aP, aQ));
        atomicAdd(&o[i1],         bU);
        atomicAdd(&o[N_PTS + i1], fmaf(gb, bP, bQ));
    }
}

extern "C" void kernel_launch(void* const* d_in, const int* in_sizes, int n_in,
                              void* d_out, int out_size, void* d_ws, size_t ws_size,
                              hipStream_t stream) {
    const float* x  = (const float*)d_in[0];
    const float* h1 = (const float*)d_in[1];
    const float* c1 = (const float*)d_in[2];
    const float* w1 = (const float*)d_in[3];
    const float* h2 = (const float*)d_in[4];
    const float* c2 = (const float*)d_in[5];
    const float* w2 = (const float*)d_in[6];
    const float* h3 = (const float*)d_in[7];
    const float* c3 = (const float*)d_in[8];
    const float* w3 = (const float*)d_in[9];

    hipMemsetAsync(d_out, 0, (size_t)out_size * sizeof(float), stream);

    // 3 sets x 4 center-chunks x 128 point-blocks
    srbf_kernel<<<dim3(3 * 4 * 128), dim3(256), 0, stream>>>(
        x, h1, c1, w1, h2, c2, w2, h3, c3, w3, (float*)d_out);
}

// Round 3
// 55.212 us; speedup vs baseline: 1.1323x; 1.1323x over previous
//
#include <hip/hip_runtime.h>
#include <math.h>

#define N_PTS  65536
#define N_CTR  1024
#define CHUNK  128          // centers per block -> 8 chunks
#define PPT    8            // points per thread
#define PPB    (256 * PPT)  // 2048 points per block

#if __has_builtin(__builtin_amdgcn_exp2f)
#define EXP2(x) __builtin_amdgcn_exp2f(x)
#else
#define EXP2(x) exp2f(x)
#endif

// Exponent as polynomial in (x, x^2, y, y^2):  s = za + zb*x + zc*x^2 + zd*y + ze*y^2
// (log2e folded). Derivative sums split into pure-FMA accumulators:
//   sum p*(x-cx)*e = x*sum(p*e) + sum((-p*cx)*e)
// P=8 points/thread amortizes the LDS broadcast reads (LDS delivers per-lane
// bytes even for uniform addresses: ~18 cyc per 36B/center/wave -> was the
// R0/R1 bottleneck at ~60us).
__global__ __launch_bounds__(256) void srbf_kernel(
    const float* __restrict__ x,
    const float* __restrict__ h0, const float* __restrict__ c0, const float* __restrict__ w0,
    const float* __restrict__ h1, const float* __restrict__ c1, const float* __restrict__ w1,
    const float* __restrict__ h2, const float* __restrict__ c2, const float* __restrict__ w2,
    float* __restrict__ out)
{
    __shared__ float4 sA[CHUNK];   // (zb, zc, zd, ze)
    __shared__ float4 sB[CHUNK];   // (za, k0, k1, k2)
    __shared__ float  sC[CHUNK];   // k3 (set 0 only)

    const int bid   = blockIdx.x;
    const int set   = bid >> 8;          // 256 blocks per set
    const int r     = bid & 255;
    const int chunk = r >> 5;            // 8 center-chunks of 128
    const int pblk  = r & 31;            // 32 point-blocks of 2048
    const int tid   = threadIdx.x;

    const float*  __restrict__ h = (set == 0) ? h0 : ((set == 1) ? h1 : h2);
    const float2* __restrict__ c = (const float2*)((set == 0) ? c0 : ((set == 1) ? c1 : c2));
    const float2* __restrict__ w = (const float2*)((set == 0) ? w0 : ((set == 1) ? w1 : w2));

    const float LOG2E = 1.4426950408889634f;

    if (tid < CHUNK) {
        const int j = chunk * CHUNK + tid;
        float2 cj = c[j];
        float2 wj = w[j];
        float  hh = h[j];
        float d1 = wj.x * wj.x;
        float d2 = wj.y * wj.y;
        float zb =  2.f * cj.x * d1 * LOG2E;
        float zc = -d1 * LOG2E;
        float zd =  2.f * cj.y * d2 * LOG2E;
        float ze = -d2 * LOG2E;
        float za = -(cj.x * cj.x * d1 + cj.y * cj.y * d2) * LOG2E;
        float k0, k1, k2, k3;
        if (set == 0) {
            k0 = -2.f * hh * d1;          // ux slope
            k1 =  2.f * hh * d1 * cj.x;   // ux offset
            k2 = -2.f * hh * d2;          // uy slope
            k3 =  2.f * hh * d2 * cj.y;   // uy offset
        } else if (set == 1) {
            k0 = hh;                       // P
            k1 = -2.f * hh * d1;          // Px slope
            k2 =  2.f * hh * d1 * cj.x;   // Px offset
            k3 = 0.f;
        } else {
            k0 = hh;                       // Q
            k1 = -2.f * hh * d2;          // Qy slope
            k2 =  2.f * hh * d2 * cj.y;   // Qy offset
            k3 = 0.f;
        }
        sA[tid] = make_float4(zb, zc, zd, ze);
        sB[tid] = make_float4(za, k0, k1, k2);
        sC[tid] = k3;
    }
    __syncthreads();

    const int base = pblk * PPB + tid;

    float X[PPT], Y[PPT], X2[PPT], Y2[PPT];
    #pragma unroll
    for (int p = 0; p < PPT; ++p) {
        float2 q = ((const float2*)x)[base + p * 256];
        X[p] = q.x;  Y[p] = q.y;
        X2[p] = q.x * q.x;  Y2[p] = q.y * q.y;
    }

    if (set == 0) {
        float A0[PPT], A1[PPT], A2[PPT], A3[PPT];
        #pragma unroll
        for (int p = 0; p < PPT; ++p) { A0[p] = A1[p] = A2[p] = A3[p] = 0.f; }

        #pragma unroll 2
        for (int j = 0; j < CHUNK; ++j) {
            float4 A = sA[j];
            float4 B = sB[j];
            float  k3 = sC[j];
            #pragma unroll
            for (int p = 0; p < PPT; ++p) {
                float s = fmaf(X[p],  A.x, B.x);
                s       = fmaf(X2[p], A.y, s);
                s       = fmaf(Y[p],  A.z, s);
                s       = fmaf(Y2[p], A.w, s);
                float e = EXP2(s);
                A0[p] = fmaf(B.y, e, A0[p]);
                A1[p] = fmaf(B.z, e, A1[p]);
                A2[p] = fmaf(B.w, e, A2[p]);
                A3[p] = fmaf(k3,  e, A3[p]);
            }
        }
        #pragma unroll
        for (int p = 0; p < PPT; ++p) {
            const int i = base + p * 256;
            atomicAdd(&out[i],         fmaf(X[p], A0[p], A1[p]));   // ux
            atomicAdd(&out[N_PTS + i], fmaf(Y[p], A2[p], A3[p]));   // uy
        }
    } else {
        float A0[PPT], A1[PPT], A2[PPT];
        #pragma unroll
        for (int p = 0; p < PPT; ++p) { A0[p] = A1[p] = A2[p] = 0.f; }

        #pragma unroll 2
        for (int j = 0; j < CHUNK; ++j) {
            float4 A = sA[j];
            float4 B = sB[j];
            #pragma unroll
            for (int p = 0; p < PPT; ++p) {
                float s = fmaf(X[p],  A.x, B.x);
                s       = fmaf(X2[p], A.y, s);
                s       = fmaf(Y[p],  A.z, s);
                s       = fmaf(Y2[p], A.w, s);
                float e = EXP2(s);
                A0[p] = fmaf(B.y, e, A0[p]);
                A1[p] = fmaf(B.z, e, A1[p]);
                A2[p] = fmaf(B.w, e, A2[p]);
            }
        }
        float* o = out + (size_t)set * 2 * N_PTS;
        #pragma unroll
        for (int p = 0; p < PPT; ++p) {
            const int i = base + p * 256;
            const float g = (set == 1) ? X[p] : Y[p];
            atomicAdd(&o[i],         A0[p]);                 // P or Q
            atomicAdd(&o[N_PTS + i], fmaf(g, A1[p], A2[p])); // Px or Qy
        }
    }
}

extern "C" void kernel_launch(void* const* d_in, const int* in_sizes, int n_in,
                              void* d_out, int out_size, void* d_ws, size_t ws_size,
                              hipStream_t stream) {
    const float* x  = (const float*)d_in[0];
    const float* h1 = (const float*)d_in[1];
    const float* c1 = (const float*)d_in[2];
    const float* w1 = (const float*)d_in[3];
    const float* h2 = (const float*)d_in[4];
    const float* c2 = (const float*)d_in[5];
    const float* w2 = (const float*)d_in[6];
    const float* h3 = (const float*)d_in[7];
    const float* c3 = (const float*)d_in[8];
    const float* w3 = (const float*)d_in[9];

    hipMemsetAsync(d_out, 0, (size_t)out_size * sizeof(float), stream);

    // 3 sets x 8 center-chunks x 32 point-blocks = 768 blocks (3/CU, 12 waves/CU)
    srbf_kernel<<<dim3(768), dim3(256), 0, stream>>>(
        x, h1, c1, w1, h2, c2, w2, h3, c3, w3, (float*)d_out);
}